// Round 3
// baseline (1510.281 us; speedup 1.0000x reference)
//
#include <hip/hip_runtime.h>
#include <hip/hip_bf16.h>
#include <math.h>

// Problem constants (fixed by reference)
#define NT  8192
#define EMB 512
#define DFF 2048
#define EPS 1e-5f
#define SCALE 0.04419417382415922f  // 1/sqrt(512)
#define NHALF (NT / 2)              // 4096 cols per split-n WG

typedef __hip_bfloat16 bf16;
typedef __attribute__((ext_vector_type(8))) short short8;
typedef __attribute__((ext_vector_type(4))) float floatx4;

#define MFMA16(a, b, c) __builtin_amdgcn_mfma_f32_16x16x32_bf16((a), (b), (c), 0, 0, 0)

// compiler-ordering barrier (no instruction): pins vmcnt queue order
#define ORDER() asm volatile("" ::: "memory")
// B1: LDS-visibility barrier; staging/loads stay in flight
#define BARRIER_LGKM() asm volatile("s_waitcnt lgkmcnt(0)\ns_barrier" ::: "memory")
// B2: drain all but the 4 newest vmem ops (= spi prefetch stays in flight)
#define BARRIER_VM4() asm volatile("s_waitcnt vmcnt(4) lgkmcnt(0)\ns_barrier" ::: "memory")

__device__ __forceinline__ void async16(const void* g, void* l) {
  __builtin_amdgcn_global_load_lds(
      (const __attribute__((address_space(1))) void*)g,
      (__attribute__((address_space(3))) void*)l, 16, 0, 0);
}

// ---------------- LayerNorm: fp32 in -> bf16 out, one row per block ----------------
__global__ __launch_bounds__(512) void ln_kernel(const float* __restrict__ in,
                                                 const float* __restrict__ g,
                                                 const float* __restrict__ b,
                                                 bf16* __restrict__ out) {
  const int row = blockIdx.x;
  const int tid = threadIdx.x;
  float v = in[(size_t)row * EMB + tid];
  float s = v, ss = v * v;
#pragma unroll
  for (int m = 1; m < 64; m <<= 1) {
    s += __shfl_xor(s, m, 64);
    ss += __shfl_xor(ss, m, 64);
  }
  __shared__ float ps[8], pss[8], mu_s, ri_s;
  const int wave = tid >> 6;
  if ((tid & 63) == 0) { ps[wave] = s; pss[wave] = ss; }
  __syncthreads();
  if (tid == 0) {
    float S = 0.f, SS = 0.f;
#pragma unroll
    for (int w = 0; w < 8; ++w) { S += ps[w]; SS += pss[w]; }
    float mu = S * (1.0f / EMB);
    float var = SS * (1.0f / EMB) - mu * mu;
    mu_s = mu;
    ri_s = rsqrtf(var + EPS);
  }
  __syncthreads();
  float y = (v - mu_s) * ri_s * g[tid] + b[tid];
  out[(size_t)row * EMB + tid] = __float2bfloat16(y);
}

// ---------------- transpose + cast to bf16: out[c][r] = in[r][c] ----------------
template <typename Tin>
__global__ void transpose_cast(const Tin* __restrict__ in, bf16* __restrict__ out,
                               int R, int C) {
  __shared__ float tile[32][33];
  const int r0 = blockIdx.x * 32, c0 = blockIdx.y * 32;
  const int x = threadIdx.x, y = threadIdx.y;  // block (32, 8)
#pragma unroll
  for (int i = 0; i < 4; ++i)
    tile[y + 8 * i][x] = (float)in[(size_t)(r0 + y + 8 * i) * C + c0 + x];
  __syncthreads();
#pragma unroll
  for (int i = 0; i < 4; ++i)
    out[(size_t)(c0 + y + 8 * i) * R + r0 + x] = __float2bfloat16(tile[x][y + 8 * i]);
}

// ---------------- Flash attention v3: split-n, 2 WG/CU, spi prefetch-ahead --------
// grid (NT/32, 2). WG (bx, s) processes Q-rows [bx*32, +32), K/V cols [s*4096, +4096),
// writing UNNORMALIZED partial O (bf16) + per-row running max m and denom l.
// 512 thr = 8 waves; S-phase wave w -> rows (w&1)*16, cols (w>>1)*16; PV d-slice 64w.
// Single-buffer K tile (64 KB LDS -> 2 WG/CU): stage tile i+1 after B1 (k_s consumed),
// drain at B2 with vmcnt(4) so the spi prefetch (next iter's bias) stays in flight.
__global__ __launch_bounds__(512, 4) void flash_attn(const bf16* __restrict__ nx,
                                                     const bf16* __restrict__ nxT,
                                                     const float* __restrict__ spi,
                                                     bf16* __restrict__ Opart,
                                                     float* __restrict__ mpart,
                                                     float* __restrict__ lpart) {
  __shared__ __align__(16) short k_s[64 * EMB];  // 64 KB single buffer
  __shared__ __align__(16) short p_s[32 * 72];   // stride 72 (pad) for PV A-frags
  __shared__ float wmax[8][16];
  __shared__ float wsum[8][16];
  __shared__ float alpha_s[32];
  __shared__ float l_s[32];

  const int tid = threadIdx.x;
  const int wave = tid >> 6;
  const int lane = tid & 63;
  const int quad = lane >> 4;
  const int l16 = lane & 15;
  const int mt = wave & 1;
  const int nt = wave >> 1;  // 0..3
  const int q0 = blockIdx.x * 32;
  const int s = blockIdx.y;
  const int nbeg = s * NHALF;
  const int nlast = nbeg + NHALF - 64;

  floatx4 O[2][4];
#pragma unroll
  for (int a = 0; a < 2; ++a)
#pragma unroll
    for (int d = 0; d < 4; ++d) O[a][d] = (floatx4){0.f, 0.f, 0.f, 0.f};
  float m_reg[4];
#pragma unroll
  for (int r = 0; r < 4; ++r) m_reg[r] = -INFINITY;
  if (tid < 32) l_s[tid] = 0.f;

  // ---- Q tile into registers: 16 A-frags (k=0..511) for rows mt*16+l16
  short8 qf[16];
  {
    const short* qp = (const short*)nx + (size_t)(q0 + mt * 16 + l16) * EMB + quad * 8;
#pragma unroll
    for (int ks = 0; ks < 16; ++ks) qf[ks] = *(const short8*)(qp + ks * 32);
  }
  ORDER();
  // ---- stage K tile 0 (async, XOR chunk swizzle; row&7 == t)
#pragma unroll
  for (int t = 0; t < 8; ++t) {
    int row = wave * 8 + t;
    async16(nx + (size_t)(nbeg + row) * EMB + ((lane ^ t) << 3), k_s + row * EMB);
  }
  ORDER();
  // ---- spi prefetch for iteration 0 (newest 4 in vm queue)
  const float* spib = spi + (size_t)(q0 + mt * 16 + quad * 4) * NT + nt * 16 + l16;
  float bias_pf[4];
#pragma unroll
  for (int r = 0; r < 4; ++r) bias_pf[r] = spib[(size_t)r * NT + nbeg];
  BARRIER_VM4();  // qf + staging drained (spi prefetch flying); l_s init visible

  const int krow = nt * 16 + l16;
  const int kx = krow & 7;
  const short* kb = k_s + krow * EMB;
  const short* vbase = (const short*)nxT + (size_t)(wave * 64 + l16) * NT + quad * 8;

  for (int n0 = nbeg; n0 < nbeg + NHALF; n0 += 64) {
    // ---- A: V-frags for THIS iter (oldest in vm queue; consumed after B2)
    short8 vf[8];
#pragma unroll
    for (int ns = 0; ns < 2; ++ns)
#pragma unroll
      for (int d = 0; d < 4; ++d)
        vf[ns * 4 + d] = *(const short8*)(vbase + (size_t)(d * 16) * NT + n0 + ns * 32);
    ORDER();

    // ---- B: S = Q K^T over k=512 (reads k_s tile i), bias from LAST iter's prefetch
    floatx4 acc0 = (floatx4){0.f, 0.f, 0.f, 0.f}, acc1 = (floatx4){0.f, 0.f, 0.f, 0.f};
#pragma unroll
    for (int ks = 0; ks < 16; ks += 2) {
      short8 b0 = *(const short8*)(kb + (((ks * 4 + quad) ^ kx) << 3));
      acc0 = MFMA16(qf[ks], b0, acc0);
      short8 b1 = *(const short8*)(kb + ((((ks + 1) * 4 + quad) ^ kx) << 3));
      acc1 = MFMA16(qf[ks + 1], b1, acc1);
    }
    float sv[4], pm[4];
#pragma unroll
    for (int r = 0; r < 4; ++r) {
      sv[r] = (acc0[r] + acc1[r]) * SCALE + bias_pf[r];
      pm[r] = sv[r];
    }
#pragma unroll
    for (int m = 1; m < 16; m <<= 1)
#pragma unroll
      for (int r = 0; r < 4; ++r) pm[r] = fmaxf(pm[r], __shfl_xor(pm[r], m, 64));
    if (l16 == 0) {
#pragma unroll
      for (int r = 0; r < 4; ++r) wmax[wave][quad * 4 + r] = pm[r];
    }
    BARRIER_LGKM();  // B1: k_s fully consumed by all waves; wmax visible

    // ---- C: stage NEXT K tile into k_s + prefetch NEXT spi bias
    const int n1 = (n0 + 64 > nlast) ? nlast : n0 + 64;  // last iter: harmless restage
#pragma unroll
    for (int t = 0; t < 8; ++t) {
      int row = wave * 8 + t;
      async16(nx + (size_t)(n1 + row) * EMB + ((lane ^ t) << 3), k_s + row * EMB);
    }
    ORDER();
#pragma unroll
    for (int r = 0; r < 4; ++r) bias_pf[r] = spib[(size_t)r * NT + n1];
    ORDER();

    // ---- D: online softmax
    float al[4], pv[4], psum[4];
#pragma unroll
    for (int r = 0; r < 4; ++r) {
      int rr = quad * 4 + r;
      float cm = fmaxf(fmaxf(wmax[mt][rr], wmax[mt + 2][rr]),
                       fmaxf(wmax[mt + 4][rr], wmax[mt + 6][rr]));
      float mn = fmaxf(m_reg[r], cm);
      al[r] = __expf(m_reg[r] - mn);
      m_reg[r] = mn;
      pv[r] = __expf(sv[r] - mn);
      psum[r] = pv[r];
    }
#pragma unroll
    for (int m = 1; m < 16; m <<= 1)
#pragma unroll
      for (int r = 0; r < 4; ++r) psum[r] += __shfl_xor(psum[r], m, 64);
    if (l16 == 0) {
#pragma unroll
      for (int r = 0; r < 4; ++r) wsum[wave][quad * 4 + r] = psum[r];
    }
#pragma unroll
    for (int r = 0; r < 4; ++r)
      ((bf16*)p_s)[(mt * 16 + quad * 4 + r) * 72 + nt * 16 + l16] = __float2bfloat16(pv[r]);
    if (wave < 2 && l16 == 0) {
#pragma unroll
      for (int r = 0; r < 4; ++r) alpha_s[mt * 16 + quad * 4 + r] = al[r];
    }
    BARRIER_VM4();  // B2: p_s/wsum/alpha visible; staging drained; spi prefetch flies

    // ---- E: l update, O rescale, PV
    if (wave < 2 && l16 == 0) {
#pragma unroll
      for (int r = 0; r < 4; ++r) {
        int rr = quad * 4 + r;
        l_s[mt * 16 + rr] = al[r] * l_s[mt * 16 + rr] + wsum[mt][rr] + wsum[mt + 2][rr] +
                            wsum[mt + 4][rr] + wsum[mt + 6][rr];
      }
    }
    float arow[2][4];
#pragma unroll
    for (int a = 0; a < 2; ++a)
#pragma unroll
      for (int r = 0; r < 4; ++r) arow[a][r] = alpha_s[a * 16 + quad * 4 + r];
#pragma unroll
    for (int a = 0; a < 2; ++a)
#pragma unroll
      for (int d = 0; d < 4; ++d)
#pragma unroll
        for (int r = 0; r < 4; ++r) O[a][d][r] *= arow[a][r];
#pragma unroll
    for (int ns = 0; ns < 2; ++ns) {
      short8 pa0 = *(const short8*)(p_s + (l16)*72 + ns * 32 + quad * 8);
      short8 pa1 = *(const short8*)(p_s + (16 + l16) * 72 + ns * 32 + quad * 8);
#pragma unroll
      for (int d = 0; d < 4; ++d) {
        O[0][d] = MFMA16(pa0, vf[ns * 4 + d], O[0][d]);
        O[1][d] = MFMA16(pa1, vf[ns * 4 + d], O[1][d]);
      }
    }
  }
  __syncthreads();
  // ---- epilogue: store unnormalized partial O (bf16) + m, l
  const size_t obase = ((size_t)s * NT + q0) * EMB;
#pragma unroll
  for (int a = 0; a < 2; ++a)
#pragma unroll
    for (int d = 0; d < 4; ++d)
#pragma unroll
      for (int r = 0; r < 4; ++r) {
        int row = a * 16 + quad * 4 + r;
        int dim = wave * 64 + d * 16 + l16;
        Opart[obase + (size_t)row * EMB + dim] = __float2bfloat16(O[a][d][r]);
      }
  if (wave < 2 && l16 == 0) {
#pragma unroll
    for (int r = 0; r < 4; ++r) {
      int row = mt * 16 + quad * 4 + r;
      mpart[s * NT + q0 + row] = m_reg[r];
      lpart[s * NT + q0 + row] = l_s[row];
    }
  }
}

// ---------------- merge split-n partials + residual + LayerNorm2 fused ----------
// out = x + (a1*O1 + a2*O2) / (a1*l1 + a2*l2);  h = LN(out, g2, b2) in bf16
__global__ __launch_bounds__(512) void merge_ln(const bf16* __restrict__ Opart,
                                                const float* __restrict__ mpart,
                                                const float* __restrict__ lpart,
                                                const float* __restrict__ x,
                                                const float* __restrict__ g,
                                                const float* __restrict__ b,
                                                float* __restrict__ out,
                                                bf16* __restrict__ h) {
  const int row = blockIdx.x;
  const int tid = threadIdx.x;
  float m1 = mpart[row], m2 = mpart[NT + row];
  float l1 = lpart[row], l2 = lpart[NT + row];
  float mm = fmaxf(m1, m2);
  float a1 = __expf(m1 - mm), a2 = __expf(m2 - mm);
  float linv = 1.0f / (a1 * l1 + a2 * l2);
  float o1 = __bfloat162float(Opart[(size_t)row * EMB + tid]);
  float o2 = __bfloat162float(Opart[((size_t)NT + row) * EMB + tid]);
  float v = x[(size_t)row * EMB + tid] + (a1 * o1 + a2 * o2) * linv;
  out[(size_t)row * EMB + tid] = v;
  // LayerNorm over the row (value already in register)
  float sum = v, ssum = v * v;
#pragma unroll
  for (int m = 1; m < 64; m <<= 1) {
    sum += __shfl_xor(sum, m, 64);
    ssum += __shfl_xor(ssum, m, 64);
  }
  __shared__ float ps[8], pss[8], mu_s, ri_s;
  const int wave = tid >> 6;
  if ((tid & 63) == 0) { ps[wave] = sum; pss[wave] = ssum; }
  __syncthreads();
  if (tid == 0) {
    float S = 0.f, SS = 0.f;
#pragma unroll
    for (int w = 0; w < 8; ++w) { S += ps[w]; SS += pss[w]; }
    float mu = S * (1.0f / EMB);
    float var = SS * (1.0f / EMB) - mu * mu;
    mu_s = mu;
    ri_s = rsqrtf(var + EPS);
  }
  __syncthreads();
  h[(size_t)row * EMB + tid] = __float2bfloat16((v - mu_s) * ri_s * g[tid] + b[tid]);
}

// ---------------- BT-GEMM: C[i][j] = sum_k A[i][k]*BT[j][k], 128x128 tile ----------------
// MODE 0: C = relu(acc + bias[j]) -> bf16    MODE 1: C = acc + bias[j] + resid -> fp32
template <int MODE>
__global__ __launch_bounds__(256) void gemm_bt(const bf16* __restrict__ A,
                                               const bf16* __restrict__ BT,
                                               const float* __restrict__ bias,
                                               const float* __restrict__ resid,
                                               void* __restrict__ Cout, int M, int Nn,
                                               int K) {
  __shared__ __align__(16) short a_s[128 * 32];
  __shared__ __align__(16) short b_s[128 * 32];
  const int tid = threadIdx.x;
  const int wave = tid >> 6, lane = tid & 63, quad = lane >> 4, l16 = lane & 15;
  const int m0 = blockIdx.x * 128, n0 = blockIdx.y * 128;
  const int mh = (wave & 1) * 64, nh = (wave >> 1) * 64;

  floatx4 acc[4][4];
#pragma unroll
  for (int i = 0; i < 4; ++i)
#pragma unroll
    for (int j = 0; j < 4; ++j) acc[i][j] = (floatx4){0.f, 0.f, 0.f, 0.f};

  for (int k0 = 0; k0 < K; k0 += 32) {
    __syncthreads();
#pragma unroll
    for (int t = 0; t < 2; ++t) {
      int c = (wave * 2 + t) * 64 + lane;  // chunk 0..511
      int row = c >> 2, pc = c & 3;
      int sc = (pc ^ ((row >> 1) & 3)) << 3;  // XOR swizzle source col
      async16(A + (size_t)(m0 + row) * K + k0 + sc, a_s + (wave * 2 + t) * 512);
      async16(BT + (size_t)(n0 + row) * K + k0 + sc, b_s + (wave * 2 + t) * 512);
    }
    __syncthreads();
    short8 af[4], bfr[4];
#pragma unroll
    for (int i = 0; i < 4; ++i) {
      int ar = mh + i * 16 + l16;
      af[i] = *(const short8*)(a_s + ar * 32 + ((quad ^ ((ar >> 1) & 3)) << 3));
      int br = nh + i * 16 + l16;
      bfr[i] = *(const short8*)(b_s + br * 32 + ((quad ^ ((br >> 1) & 3)) << 3));
    }
#pragma unroll
    for (int i = 0; i < 4; ++i)
#pragma unroll
      for (int j = 0; j < 4; ++j) acc[i][j] = MFMA16(af[i], bfr[j], acc[i][j]);
  }
#pragma unroll
  for (int i = 0; i < 4; ++i)
#pragma unroll
    for (int j = 0; j < 4; ++j)
#pragma unroll
      for (int r = 0; r < 4; ++r) {
        int row = m0 + mh + i * 16 + quad * 4 + r;
        int col = n0 + nh + j * 16 + l16;
        float v = acc[i][j][r] + bias[col];
        if (MODE == 0) {
          ((bf16*)Cout)[(size_t)row * Nn + col] = __float2bfloat16(fmaxf(v, 0.f));
        } else {
          size_t idx = (size_t)row * Nn + col;
          ((float*)Cout)[idx] = v + resid[idx];
        }
      }
}

// ---------------- launch ----------------
extern "C" void kernel_launch(void* const* d_in, const int* in_sizes, int n_in,
                              void* d_out, int out_size, void* d_ws, size_t ws_size,
                              hipStream_t stream) {
  const float* x = (const float*)d_in[0];
  // d_in[1] = edge_weights (unused by reference)
  const float* spi = (const float*)d_in[2];
  const float* g1 = (const float*)d_in[3];
  const float* b1 = (const float*)d_in[4];
  const float* g2 = (const float*)d_in[5];
  const float* b2 = (const float*)d_in[6];
  const float* W1 = (const float*)d_in[7];
  const float* bb1 = (const float*)d_in[8];
  const float* W2 = (const float*)d_in[9];
  const float* bb2 = (const float*)d_in[10];
  float* out = (float*)d_out;

  // workspace layout (60 MB total):
  //  [0,8) nx  [8,16) nxT  [16,24) h  [24,56) t (FFN mid, 32MB)  [56,58) w1t  [58,60) w2t
  //  Opart (16.78 MB bf16) + mpart/lpart alias the t region (dead before gemm0 writes t)
  char* ws = (char*)d_ws;
  bf16* nx = (bf16*)(ws);
  bf16* nxT = (bf16*)(ws + (8ull << 20));
  bf16* h = (bf16*)(ws + (16ull << 20));
  bf16* t = (bf16*)(ws + (24ull << 20));
  bf16* Opart = (bf16*)(ws + (24ull << 20));          // 2*8192*512*2 = 16.78 MB
  float* mpart = (float*)(ws + (42ull << 20));        // 64 KB
  float* lpart = (float*)(ws + (42ull << 20) + (1ull << 18));  // 64 KB
  bf16* w1t = (bf16*)(ws + (56ull << 20));
  bf16* w2t = (bf16*)(ws + (58ull << 20));

  ln_kernel<<<NT, 512, 0, stream>>>(x, g1, b1, nx);
  transpose_cast<bf16><<<dim3(NT / 32, EMB / 32), dim3(32, 8), 0, stream>>>(nx, nxT, NT, EMB);
  transpose_cast<float><<<dim3(EMB / 32, DFF / 32), dim3(32, 8), 0, stream>>>(W1, w1t, EMB, DFF);
  transpose_cast<float><<<dim3(DFF / 32, EMB / 32), dim3(32, 8), 0, stream>>>(W2, w2t, DFF, EMB);
  flash_attn<<<dim3(NT / 32, 2), 512, 0, stream>>>(nx, nxT, spi, Opart, mpart, lpart);
  merge_ln<<<NT, 512, 0, stream>>>(Opart, mpart, lpart, x, g2, b2, out, h);
  gemm_bt<0><<<dim3(NT / 128, DFF / 128), 256, 0, stream>>>(h, w1t, bb1, nullptr, (void*)t, NT, DFF, EMB);
  gemm_bt<1><<<dim3(NT / 128, EMB / 128), 256, 0, stream>>>(t, w2t, bb2, out, (void*)out, NT, EMB, DFF);
}

// Round 4
// 731.354 us; speedup vs baseline: 2.0650x; 2.0650x over previous
//
#include <hip/hip_runtime.h>
#include <hip/hip_bf16.h>
#include <math.h>

// Problem constants (fixed by reference)
#define NT  8192
#define EMB 512
#define DFF 2048
#define EPS 1e-5f
#define SCALE 0.04419417382415922f  // 1/sqrt(512)

typedef __hip_bfloat16 bf16;
typedef __attribute__((ext_vector_type(8))) short short8;
typedef __attribute__((ext_vector_type(4))) float floatx4;

#define MFMA_BF16(a, b, c) __builtin_amdgcn_mfma_f32_16x16x32_bf16((a), (b), (c), 0, 0, 0)
#define MFMA_FP8(a, b, c)  __builtin_amdgcn_mfma_f32_16x16x32_fp8_fp8((a), (b), (c), 0, 0, 0)

// B1: LDS-visibility barrier only; global/staging loads stay in flight
#define BARRIER_LGKM() asm volatile("s_waitcnt lgkmcnt(0)\ns_barrier" ::: "memory")
// B2: drain everything
#define BARRIER_ALL()  asm volatile("s_waitcnt vmcnt(0) lgkmcnt(0)\ns_barrier" ::: "memory")

__device__ __forceinline__ void async16(const void* g, void* l) {
  __builtin_amdgcn_global_load_lds(
      (const __attribute__((address_space(1))) void*)g,
      (__attribute__((address_space(3))) void*)l, 16, 0, 0);
}

// ---------------- LayerNorm1: fp32 in -> bf16 + fp8(e4m3) out ----------------
__global__ __launch_bounds__(512) void ln_kernel(const float* __restrict__ in,
                                                 const float* __restrict__ g,
                                                 const float* __restrict__ b,
                                                 bf16* __restrict__ out,
                                                 unsigned char* __restrict__ out8) {
  const int row = blockIdx.x;
  const int tid = threadIdx.x;
  float v = in[(size_t)row * EMB + tid];
  float s = v, ss = v * v;
#pragma unroll
  for (int m = 1; m < 64; m <<= 1) {
    s += __shfl_xor(s, m, 64);
    ss += __shfl_xor(ss, m, 64);
  }
  __shared__ float ps[8], pss[8], mu_s, ri_s;
  const int wave = tid >> 6;
  if ((tid & 63) == 0) { ps[wave] = s; pss[wave] = ss; }
  __syncthreads();
  if (tid == 0) {
    float S = 0.f, SS = 0.f;
#pragma unroll
    for (int w = 0; w < 8; ++w) { S += ps[w]; SS += pss[w]; }
    float mu = S * (1.0f / EMB);
    float var = SS * (1.0f / EMB) - mu * mu;
    mu_s = mu;
    ri_s = rsqrtf(var + EPS);
  }
  __syncthreads();
  float y = (v - mu_s) * ri_s * g[tid] + b[tid];
  out[(size_t)row * EMB + tid] = __float2bfloat16(y);
  int p8 = __builtin_amdgcn_cvt_pk_fp8_f32(y, y, 0, false);
  out8[(size_t)row * EMB + tid] = (unsigned char)(p8 & 0xff);
}

// ---------------- transpose + cast to bf16: out[c][r] = in[r][c] ----------------
template <typename Tin>
__global__ void transpose_cast(const Tin* __restrict__ in, bf16* __restrict__ out,
                               int R, int C) {
  __shared__ float tile[32][33];
  const int r0 = blockIdx.x * 32, c0 = blockIdx.y * 32;
  const int x = threadIdx.x, y = threadIdx.y;  // block (32, 8)
#pragma unroll
  for (int i = 0; i < 4; ++i)
    tile[y + 8 * i][x] = (float)in[(size_t)(r0 + y + 8 * i) * C + c0 + x];
  __syncthreads();
#pragma unroll
  for (int i = 0; i < 4; ++i)
    out[(size_t)(c0 + y + 8 * i) * R + r0 + x] = __float2bfloat16(tile[x][y + 8 * i]);
}

// ---------------- Flash attention v4 ----------------
// S^T orientation: S^T[n][q] = sum_k K8[n][k] Q8[q][k] via MFMA(A=K-frag, B=Q-frag), fp8.
// BM=64 Q-rows/WG, BN=64 cols/iter, split-n 2-way INTERLEAVED (cohort s takes tiles 2i+s).
// 8 waves: qt=wave&3 (16-q slice for softmax), nh=wave>>2 (32-n half).
// PV: wave owns d-slice [wave*64, +64), all 64 q. Unnormalized O + (m,l) partials out.
__global__ __launch_bounds__(512, 2) void flash_attn(const unsigned char* __restrict__ nx8,
                                                     const bf16* __restrict__ nxT,
                                                     const float* __restrict__ spi,
                                                     bf16* __restrict__ Opart,
                                                     float* __restrict__ mpart,
                                                     float* __restrict__ lpart) {
  // LDS layout (bytes): k8[0,32768) | p_s[32768,43008) | wmax/wsum/alpha[43008,...)
  __shared__ __align__(16) char smem[44352];
  char* k8 = smem;                       // 64 rows x 512 B fp8, 16B-chunk XOR swizzle
  short* p_s = (short*)(smem + 32768);   // [64 q][80 n-pad] bf16
  float* wmax = (float*)(smem + 43008);  // [2][64]
  float* wsum = (float*)(smem + 43520);  // [2][64]
  float* alpha_s = (float*)(smem + 44032);  // [64]

  const int tid = threadIdx.x;
  const int wave = tid >> 6;
  const int lane = tid & 63;
  const int quad = lane >> 4;
  const int l16 = lane & 15;
  const int qh = quad >> 1;   // chunk16 half
  const int qt = wave & 3;    // q-slice for S/softmax
  const int nh = wave >> 2;   // n-half for S
  const int q0 = blockIdx.x * 64;
  const int s = blockIdx.y;

  floatx4 O[4][4];  // [qt2][dt] rows qt2*16+quad*4+r, dim wave*64+dt*16+l16
#pragma unroll
  for (int i = 0; i < 4; ++i)
#pragma unroll
    for (int j = 0; j < 4; ++j) O[i][j] = (floatx4){0.f, 0.f, 0.f, 0.f};
  float m_reg = -INFINITY;  // per-lane: q = qt*16+l16 (quad-replicated)
  float l_reg = 0.f;

  // ---- Q fp8 B-frags in regs: q row = q0 + qt*16 + l16, k = ks*32 + quad*8
  long qf8[16];
  {
    const char* qsrc = (const char*)nx8 + (size_t)(q0 + qt * 16 + l16) * EMB + quad * 8;
#pragma unroll
    for (int ks = 0; ks < 16; ++ks) qf8[ks] = *(const long*)(qsrc + ks * 32);
  }
  // ---- stage K tile 0 (fp8, async DMA, 16B-chunk XOR swizzle)
  {
    const int n0 = s * 64;
#pragma unroll
    for (int t = 0; t < 4; ++t) {
      int c = t * 512 + tid;
      int row = c >> 5, ch = c & 31;
      async16(nx8 + (size_t)(n0 + row) * EMB + ((ch ^ (row & 7)) << 4), k8 + c * 16);
    }
  }
  // ---- spi bias prefetch for iter 0: lane -> q=qt*16+l16, n = n0 + nh*32 + nt2*16 + quad*4
  const float* spib = spi + (size_t)(q0 + qt * 16 + l16) * NT + nh * 32 + quad * 4;
  floatx4 bias_pf[2];
  {
    const int n0 = s * 64;
    bias_pf[0] = *(const floatx4*)(spib + n0);
    bias_pf[1] = *(const floatx4*)(spib + n0 + 16);
  }
  BARRIER_ALL();

  // A-frag LDS bases: rows nh*32 + nt2*16 + l16
  const char* kb0 = k8 + (nh * 32 + l16) * 512 + (quad & 1) * 8;
  const char* kb1 = kb0 + 16 * 512;
  const int rx = l16 & 7;  // row&7 (nh*32, +16 are mult of 8)
  const short* vbase = (const short*)nxT + (size_t)(wave * 64 + l16) * NT + quad * 8;

  const int nlaststep = 63 * 128 + s * 64;
  for (int i = 0; i < 64; ++i) {
    const int n0 = s * 64 + i * 128;
    const int nn = (n0 == nlaststep) ? n0 : n0 + 128;

    // ---- V-frags for THIS iter (bf16, from nxT; drained at B2)
    short8 vf[8];
#pragma unroll
    for (int ks2 = 0; ks2 < 2; ++ks2)
#pragma unroll
      for (int dt = 0; dt < 4; ++dt)
        vf[ks2 * 4 + dt] = *(const short8*)(vbase + (size_t)(dt * 16) * NT + n0 + ks2 * 32);

    // ---- QK: S^T tiles (2 per wave), A=K8 from LDS, B=Q8 regs
    floatx4 acc0 = (floatx4){0.f, 0.f, 0.f, 0.f}, acc1 = (floatx4){0.f, 0.f, 0.f, 0.f};
#pragma unroll
    for (int ks = 0; ks < 16; ++ks) {
      const int off = ((ks * 2 + qh) ^ rx) << 4;
      long a0 = *(const long*)(kb0 + off);
      acc0 = MFMA_FP8(a0, qf8[ks], acc0);
      long a1 = *(const long*)(kb1 + off);
      acc1 = MFMA_FP8(a1, qf8[ks], acc1);
    }
    // sv[8]: n = nh*32 + nt2*16 + quad*4 + r, q = qt*16+l16
    float sv[8];
#pragma unroll
    for (int r = 0; r < 4; ++r) {
      sv[r] = acc0[r] * SCALE + bias_pf[0][r];
      sv[4 + r] = acc1[r] * SCALE + bias_pf[1][r];
    }
    // in-lane max over 8, then across quads (lanes with same l16)
    float pm = fmaxf(fmaxf(fmaxf(sv[0], sv[1]), fmaxf(sv[2], sv[3])),
                     fmaxf(fmaxf(sv[4], sv[5]), fmaxf(sv[6], sv[7])));
    pm = fmaxf(pm, __shfl_xor(pm, 16, 64));
    pm = fmaxf(pm, __shfl_xor(pm, 32, 64));
    if (quad == 0) wmax[nh * 64 + qt * 16 + l16] = pm;
    BARRIER_LGKM();  // B1: all QK LDS reads done; wmax visible

    // ---- stage NEXT K tile + prefetch NEXT spi bias (in flight until B2)
#pragma unroll
    for (int t = 0; t < 4; ++t) {
      int c = t * 512 + tid;
      int row = c >> 5, ch = c & 31;
      async16(nx8 + (size_t)(nn + row) * EMB + ((ch ^ (row & 7)) << 4), k8 + c * 16);
    }
    bias_pf[0] = *(const floatx4*)(spib + nn);
    bias_pf[1] = *(const floatx4*)(spib + nn + 16);

    // ---- softmax (per-lane state, quad-replicated)
    const int q = qt * 16 + l16;
    float tm = fmaxf(wmax[q], wmax[64 + q]);
    float mn = fmaxf(m_reg, tm);
    float al = __expf(m_reg - mn);
    m_reg = mn;
    float pv[8], psum = 0.f;
#pragma unroll
    for (int k = 0; k < 8; ++k) {
      pv[k] = __expf(sv[k] - mn);
      psum += pv[k];
    }
    psum += __shfl_xor(psum, 16, 64);
    psum += __shfl_xor(psum, 32, 64);
    if (quad == 0) {
      wsum[nh * 64 + q] = psum;
      if (nh == 0) alpha_s[q] = al;
    }
    // P tiles -> p_s[q][n] packed (4 consecutive n per write)
#pragma unroll
    for (int nt2 = 0; nt2 < 2; ++nt2) {
      union { short s4[4]; long l; } pk;
#pragma unroll
      for (int r = 0; r < 4; ++r)
        pk.s4[r] = __bfloat16_as_short(__float2bfloat16(pv[nt2 * 4 + r]));
      *(long*)(p_s + q * 80 + nh * 32 + nt2 * 16 + quad * 4) = pk.l;
    }
    BARRIER_ALL();  // B2: p_s/wsum/alpha visible; staging + vf drained

    l_reg = al * l_reg + wsum[q] + wsum[64 + q];

    // ---- O rescale (skip when all alphas == 1)
    floatx4 a4[4];
#pragma unroll
    for (int qt2 = 0; qt2 < 4; ++qt2)
      a4[qt2] = *(const floatx4*)(alpha_s + qt2 * 16 + quad * 4);
    int allone = 1;
#pragma unroll
    for (int qt2 = 0; qt2 < 4; ++qt2)
#pragma unroll
      for (int r = 0; r < 4; ++r) allone &= (a4[qt2][r] == 1.0f);
    if (!__all(allone)) {
#pragma unroll
      for (int qt2 = 0; qt2 < 4; ++qt2)
#pragma unroll
        for (int dt = 0; dt < 4; ++dt)
#pragma unroll
          for (int r = 0; r < 4; ++r) O[qt2][dt][r] *= a4[qt2][r];
    }
    // ---- PV: O += P @ V (A=P from p_s, B=V regs)
#pragma unroll
    for (int qt2 = 0; qt2 < 4; ++qt2) {
      short8 pa0 = *(const short8*)(p_s + (qt2 * 16 + l16) * 80 + quad * 8);
      short8 pa1 = *(const short8*)(p_s + (qt2 * 16 + l16) * 80 + 32 + quad * 8);
#pragma unroll
      for (int dt = 0; dt < 4; ++dt) {
        O[qt2][dt] = MFMA_BF16(pa0, vf[dt], O[qt2][dt]);
        O[qt2][dt] = MFMA_BF16(pa1, vf[4 + dt], O[qt2][dt]);
      }
    }
  }
  __syncthreads();

  // ---- epilogue: coalesced bf16 store via LDS bounce (2 passes of 32 q-rows)
  short* ebuf = (short*)smem;  // [32][520]
#pragma unroll
  for (int p = 0; p < 2; ++p) {
    __syncthreads();
#pragma unroll
    for (int h = 0; h < 2; ++h) {
      const int qt2 = 2 * p + h;
      const int lrow = h * 16 + quad * 4;
#pragma unroll
      for (int dt = 0; dt < 4; ++dt)
#pragma unroll
        for (int r = 0; r < 4; ++r)
          ebuf[(lrow + r) * 520 + wave * 64 + dt * 16 + l16] =
              __bfloat16_as_short(__float2bfloat16(O[qt2][dt][r]));
    }
    __syncthreads();
#pragma unroll
    for (int t = 0; t < 4; ++t) {
      int c = t * 512 + tid;
      int row = c >> 6, ch = c & 63;
      short8 v = *(const short8*)(ebuf + row * 520 + ch * 8);
      *(short8*)((short*)Opart + ((size_t)s * NT + q0 + p * 32 + row) * EMB + ch * 8) = v;
    }
  }
  if (nh == 0 && quad == 0) {
    mpart[s * NT + q0 + qt * 16 + l16] = m_reg;
    lpart[s * NT + q0 + qt * 16 + l16] = l_reg;
  }
}

// ---------------- merge split-n partials + residual + LayerNorm2 fused ----------
__global__ __launch_bounds__(512) void merge_ln(const bf16* __restrict__ Opart,
                                                const float* __restrict__ mpart,
                                                const float* __restrict__ lpart,
                                                const float* __restrict__ x,
                                                const float* __restrict__ g,
                                                const float* __restrict__ b,
                                                float* __restrict__ out,
                                                bf16* __restrict__ h) {
  const int row = blockIdx.x;
  const int tid = threadIdx.x;
  float m1 = mpart[row], m2 = mpart[NT + row];
  float l1 = lpart[row], l2 = lpart[NT + row];
  float mm = fmaxf(m1, m2);
  float a1 = __expf(m1 - mm), a2 = __expf(m2 - mm);
  float linv = 1.0f / (a1 * l1 + a2 * l2);
  float o1 = __bfloat162float(Opart[(size_t)row * EMB + tid]);
  float o2 = __bfloat162float(Opart[((size_t)NT + row) * EMB + tid]);
  float v = x[(size_t)row * EMB + tid] + (a1 * o1 + a2 * o2) * linv;
  out[(size_t)row * EMB + tid] = v;
  float sum = v, ssum = v * v;
#pragma unroll
  for (int m = 1; m < 64; m <<= 1) {
    sum += __shfl_xor(sum, m, 64);
    ssum += __shfl_xor(ssum, m, 64);
  }
  __shared__ float ps[8], pss[8], mu_s, ri_s;
  const int wave = tid >> 6;
  if ((tid & 63) == 0) { ps[wave] = sum; pss[wave] = ssum; }
  __syncthreads();
  if (tid == 0) {
    float S = 0.f, SS = 0.f;
#pragma unroll
    for (int w = 0; w < 8; ++w) { S += ps[w]; SS += pss[w]; }
    float mu = S * (1.0f / EMB);
    float var = SS * (1.0f / EMB) - mu * mu;
    mu_s = mu;
    ri_s = rsqrtf(var + EPS);
  }
  __syncthreads();
  h[(size_t)row * EMB + tid] = __float2bfloat16((v - mu_s) * ri_s * g[tid] + b[tid]);
}

// ---------------- BT-GEMM: C[i][j] = sum_k A[i][k]*BT[j][k], 128x128 tile ----------------
template <int MODE>
__global__ __launch_bounds__(256) void gemm_bt(const bf16* __restrict__ A,
                                               const bf16* __restrict__ BT,
                                               const float* __restrict__ bias,
                                               const float* __restrict__ resid,
                                               void* __restrict__ Cout, int M, int Nn,
                                               int K) {
  __shared__ __align__(16) short a_s[128 * 32];
  __shared__ __align__(16) short b_s[128 * 32];
  const int tid = threadIdx.x;
  const int wave = tid >> 6, lane = tid & 63, quad = lane >> 4, l16 = lane & 15;
  const int m0 = blockIdx.x * 128, n0 = blockIdx.y * 128;
  const int mh = (wave & 1) * 64, nh = (wave >> 1) * 64;

  floatx4 acc[4][4];
#pragma unroll
  for (int i = 0; i < 4; ++i)
#pragma unroll
    for (int j = 0; j < 4; ++j) acc[i][j] = (floatx4){0.f, 0.f, 0.f, 0.f};

  for (int k0 = 0; k0 < K; k0 += 32) {
    __syncthreads();
#pragma unroll
    for (int t = 0; t < 2; ++t) {
      int c = (wave * 2 + t) * 64 + lane;
      int row = c >> 2, pc = c & 3;
      int sc = (pc ^ ((row >> 1) & 3)) << 3;
      async16(A + (size_t)(m0 + row) * K + k0 + sc, a_s + (wave * 2 + t) * 512);
      async16(BT + (size_t)(n0 + row) * K + k0 + sc, b_s + (wave * 2 + t) * 512);
    }
    __syncthreads();
    short8 af[4], bfr[4];
#pragma unroll
    for (int i = 0; i < 4; ++i) {
      int ar = mh + i * 16 + l16;
      af[i] = *(const short8*)(a_s + ar * 32 + ((quad ^ ((ar >> 1) & 3)) << 3));
      int br = nh + i * 16 + l16;
      bfr[i] = *(const short8*)(b_s + br * 32 + ((quad ^ ((br >> 1) & 3)) << 3));
    }
#pragma unroll
    for (int i = 0; i < 4; ++i)
#pragma unroll
      for (int j = 0; j < 4; ++j) acc[i][j] = MFMA_BF16(af[i], bfr[j], acc[i][j]);
  }
#pragma unroll
  for (int i = 0; i < 4; ++i)
#pragma unroll
    for (int j = 0; j < 4; ++j)
#pragma unroll
      for (int r = 0; r < 4; ++r) {
        int row = m0 + mh + i * 16 + quad * 4 + r;
        int col = n0 + nh + j * 16 + l16;
        float v = acc[i][j][r] + bias[col];
        if (MODE == 0) {
          ((bf16*)Cout)[(size_t)row * Nn + col] = __float2bfloat16(fmaxf(v, 0.f));
        } else {
          size_t idx = (size_t)row * Nn + col;
          ((float*)Cout)[idx] = v + resid[idx];
        }
      }
}

// ---------------- launch ----------------
extern "C" void kernel_launch(void* const* d_in, const int* in_sizes, int n_in,
                              void* d_out, int out_size, void* d_ws, size_t ws_size,
                              hipStream_t stream) {
  const float* x = (const float*)d_in[0];
  const float* spi = (const float*)d_in[2];
  const float* g1 = (const float*)d_in[3];
  const float* b1 = (const float*)d_in[4];
  const float* g2 = (const float*)d_in[5];
  const float* b2 = (const float*)d_in[6];
  const float* W1 = (const float*)d_in[7];
  const float* bb1 = (const float*)d_in[8];
  const float* W2 = (const float*)d_in[9];
  const float* bb2 = (const float*)d_in[10];
  float* out = (float*)d_out;

  // ws (60 MB): nx[0,8) nxT[8,16) h[16,24) t/Opart[24,56) w1t[56,58) w2t[58,60)
  // nx8 (4 MB fp8) aliases the h region (dead until merge_ln, which runs after flash).
  // Opart (16.78 MB) + mpart/lpart alias t (dead until gemm0).
  char* ws = (char*)d_ws;
  bf16* nx = (bf16*)(ws);
  bf16* nxT = (bf16*)(ws + (8ull << 20));
  unsigned char* nx8 = (unsigned char*)(ws + (16ull << 20));
  bf16* h = (bf16*)(ws + (16ull << 20));
  bf16* t = (bf16*)(ws + (24ull << 20));
  bf16* Opart = (bf16*)(ws + (24ull << 20));
  float* mpart = (float*)(ws + (42ull << 20));
  float* lpart = (float*)(ws + (42ull << 20) + (1ull << 18));
  bf16* w1t = (bf16*)(ws + (56ull << 20));
  bf16* w2t = (bf16*)(ws + (58ull << 20));

  ln_kernel<<<NT, 512, 0, stream>>>(x, g1, b1, nx, nx8);
  transpose_cast<bf16><<<dim3(NT / 32, EMB / 32), dim3(32, 8), 0, stream>>>(nx, nxT, NT, EMB);
  transpose_cast<float><<<dim3(EMB / 32, DFF / 32), dim3(32, 8), 0, stream>>>(W1, w1t, EMB, DFF);
  transpose_cast<float><<<dim3(DFF / 32, EMB / 32), dim3(32, 8), 0, stream>>>(W2, w2t, DFF, EMB);
  flash_attn<<<dim3(NT / 64, 2), 512, 0, stream>>>(nx8, nxT, spi, Opart, mpart, lpart);
  merge_ln<<<NT, 512, 0, stream>>>(Opart, mpart, lpart, x, g2, b2, out, h);
  gemm_bt<0><<<dim3(NT / 128, DFF / 128), 256, 0, stream>>>(h, w1t, bb1, nullptr, (void*)t, NT, DFF, EMB);
  gemm_bt<1><<<dim3(NT / 128, EMB / 128), 256, 0, stream>>>(t, w2t, bb2, out, (void*)out, NT, EMB, DFF);
}